// Round 5
// baseline (295.340 us; speedup 1.0000x reference)
//
#include <hip/hip_runtime.h>
#include <hip/hip_bf16.h>

#define B_    2
#define N_    4096
#define NV_   32768
#define HID_  128
#define XD_   128
#define YD_   128
#define ZD_   16
#define PLANE (XD_*YD_*ZD_)      // 262144
#define LOCS  (B_*PLANE)         // 524288
#define STEP  (100.0f/15.0f)
#define NT    64                 // K-tile
#define VB    64                 // v rows per block
#define KS    4                  // K-split factor
#define L2E   1.4426950408889634f

typedef __attribute__((ext_vector_type(8))) short short8;
typedef __attribute__((ext_vector_type(4))) float f32x4;

__device__ __forceinline__ float anchor_coord(int i) {
    return fmaf((float)i, STEP, -50.0f);
}
// log2e-scaled anchor coordinate: distances in these coords are d*log2e,
// so softmax exp() becomes a bare v_exp_f32 (2^x).
__device__ __forceinline__ float anchor_s(int i) {
    return fmaf((float)i, STEP * L2E, -50.0f * L2E);
}
__device__ __forceinline__ float fexp2(float x) {
    float r; asm("v_exp_f32 %0, %1" : "=v"(r) : "v"(x)); return r;
}
__device__ __forceinline__ unsigned short f2bf(float x) {
    unsigned u = __float_as_uint(x);
    return (unsigned short)((u + 0x7fffu + ((u >> 16) & 1u)) >> 16);
}

// ---------------- MLP: x = relu(in @ W1 + b1) @ W2 + b2 -> xwT bf16 [b][d][n] ----------------
__global__ __launch_bounds__(256) void mlp_kernel(
    const float* __restrict__ pos, const float* __restrict__ scl,
    const float* __restrict__ rot, const float* __restrict__ opa,
    const float* __restrict__ W1,  const float* __restrict__ b1,
    const float* __restrict__ W2,  const float* __restrict__ b2,
    unsigned short* __restrict__ xwT)
{
    int rg = threadIdx.x >> 7;       // 0..1
    int j  = threadIdx.x & 127;
    int r  = blockIdx.x * 2 + rg;    // row in [0, B*N)
    __shared__ float sin_[2][11];
    __shared__ float h[2][HID_];
    if (j < 11) {
        float val;
        if (j < 3)       val = pos[r*3 + j];
        else if (j < 6)  val = scl[r*3 + (j-3)];
        else if (j < 10) val = rot[r*4 + (j-6)];
        else             val = opa[r];
        sin_[rg][j] = val;
    }
    __syncthreads();
    float a = b1[j];
    #pragma unroll
    for (int i = 0; i < 11; ++i) a = fmaf(sin_[rg][i], W1[i*HID_ + j], a);
    h[rg][j] = fmaxf(a, 0.0f);
    __syncthreads();
    float o = b2[j];
    for (int k = 0; k < HID_; ++k) o = fmaf(h[rg][k], W2[k*HID_ + j], o);
    int b = r >> 12, n = r & 4095;
    xwT[((size_t)(b*HID_ + j))*N_ + n] = f2bf(o);
}

// ------------- scatter: winner map + wave-aggregated batch buckets -------------
__global__ __launch_bounds__(256) void scatter_kernel(
    const int* __restrict__ vc, int* __restrict__ map,
    int* __restrict__ cnt, int* __restrict__ vlist)
{
    int v = blockIdx.x * 256 + threadIdx.x;
    int4 c = ((const int4*)vc)[v];
    int loc = ((c.x*XD_ + c.y)*YD_ + c.z)*ZD_ + c.w;
    atomicMax(&map[loc], v);
    int lane = threadIdx.x & 63;
    unsigned long long m1 = __ballot(c.x != 0);
    unsigned long long mymask = c.x ? m1 : ~m1;
    int leader = (int)__ffsll(mymask) - 1;
    int total  = __popcll(mymask);
    int rank   = __popcll(mymask & ((1ull << lane) - 1ull));
    int base = 0;
    if (lane == leader) base = atomicAdd(&cnt[c.x], total);
    base = __shfl(base, leader);
    vlist[c.x*NV_ + base + rank] = v;
}

// ------------- pass A: per-v (m_l2e, 1/l) single online pass, 8 lanes per v -------------
__global__ __launch_bounds__(256) void ml_kernel(
    const int* __restrict__ vc, float2* __restrict__ ml)
{
    int gid = blockIdx.x * 256 + threadIdx.x;
    int v = gid >> 3, sub = gid & 7;
    int4 c = ((const int4*)vc)[v];
    float vx = (float)c.y * L2E, vy = (float)c.z * L2E, vz = (float)c.w * L2E;
    float dz2_[16];
    #pragma unroll 16
    for (int iz = 0; iz < 16; ++iz) { float t = vz - anchor_s(iz); dz2_[iz] = t*t; }

    float m = 1e30f, l = 0.0f;
    #pragma unroll
    for (int i = 0; i < 2; ++i) {
        float dx = vx - anchor_s(sub*2 + i);
        float dx2 = dx*dx;
        for (int iy = 0; iy < 16; ++iy) {
            float dy = vy - anchor_s(iy);
            float bxy = fmaf(dy, dy, dx2);
            #pragma unroll 16
            for (int iz = 0; iz < 16; ++iz) {
                float d = sqrtf(bxy + dz2_[iz]);
                float dm = d - m;
                float e = fexp2(-fabsf(dm));
                bool nm = dm < 0.0f;
                l = nm ? fmaf(l, e, 1.0f) : (l + e);
                m = nm ? d : m;
            }
        }
    }
    #pragma unroll
    for (int off = 1; off < 8; off <<= 1) {
        float m2 = __shfl_xor(m, off);
        float l2 = __shfl_xor(l, off);
        float mn = fminf(m, m2);
        l = l * fexp2(mn - m) + l2 * fexp2(mn - m2);
        m = mn;
    }
    if (sub == 0) ml[v] = make_float2(m, 1.0f / l);
}

// ------------- pass B: partial[ks][v,:] = sum_{n in kseg} p(v,n) * x[b_v,n,:] via bf16 MFMA -------------
// Grid: [seg][vblock][kseg]. Disjoint partial buffers, plain stores (no atomics).
__global__ __launch_bounds__(256) void fuse_kernel(
    const unsigned short* __restrict__ xwT, const float2* __restrict__ ml,
    const int* __restrict__ vc,   const int* __restrict__ vlist,
    const int* __restrict__ cnt,  float* __restrict__ fused_p)
{
    int bid = blockIdx.x;
    int ks_ = bid & (KS-1);
    int rest = bid >> 2;
    int seg = rest >> 9;
    int bi  = rest & 511;
    int count = cnt[seg];
    int vbase = bi * VB;
    if (vbase >= count) return;
    int nv = min(VB, count - vbase);
    int k0 = ks_ * (N_/KS);

    __shared__ uint4 sXT[128*8];   // X^T tile: 128 d x 64 k bf16, 16B-block swizzled
    __shared__ uint4 sP [64*8];    // P  tile:  64 v x 64 k bf16, swizzled
    __shared__ float svx[VB], svy[VB], svz[VB], sdm[VB];
    __shared__ int   svid[VB];

    int tid = threadIdx.x;
    if (tid < VB) {
        int vid = -1; float fx=0, fy=0, fz=0, dm=0;
        if (tid < nv) {
            vid = vlist[seg*NV_ + vbase + tid];
            int4 c = ((const int4*)vc)[vid];
            fx = (float)c.y * L2E; fy = (float)c.z * L2E; fz = (float)c.w * L2E;
            dm = ml[vid].x;
        }
        svid[tid]=vid; svx[tid]=fx; svy[tid]=fy; svz[tid]=fz; sdm[tid]=dm;
    }
    __syncthreads();

    // P-compute assignment: v = tid&63, n-chunk = tid>>6 (16 consecutive n)
    int pv = tid & 63, png = tid >> 6;
    float pvx = svx[pv], pvy = svy[pv], pvz = svz[pv];
    float pml = sdm[pv];
    float dz2_[16];
    #pragma unroll 16
    for (int iz = 0; iz < 16; ++iz) { float t = pvz - anchor_s(iz); dz2_[iz] = t*t; }

    // wave/fragment ids
    int wv = tid >> 6, L = tid & 63;
    int wr = wv >> 1, wc = wv & 1;       // 2x2: wr = v-half, wc = d-half
    int r  = L & 15,  g  = L >> 4;
    f32x4 acc[2][4];
    #pragma unroll
    for (int i = 0; i < 2; ++i)
        #pragma unroll
        for (int jj = 0; jj < 4; ++jj) acc[i][jj] = (f32x4){0.f,0.f,0.f,0.f};

    // staging assignment: d-row = tid>>1, half = tid&1 (32 bf16 = 4x16B each)
    int sd = tid >> 1, ss = tid & 1;
    const uint4* xg = (const uint4*)xwT + ((size_t)(seg*128 + sd) * N_ >> 3);

    for (int t = 0; t < (N_/KS)/NT; ++t) {
        int n0 = k0 + t * NT;
        __syncthreads();
        // ---- stage X^T tile (global -> swizzled LDS) ----
        {
            const uint4* src = xg + (n0 >> 3) + ss*4;
            int dbase = sd * 8;
            #pragma unroll
            for (int i = 0; i < 4; ++i) {
                int blk = ss*4 + i;
                sXT[dbase + (blk ^ (sd & 7))] = src[i];
            }
        }
        // ---- compute P chunk: 16 n at nc = n0 + png*16 ----
        {
            int nc = n0 + png*16;
            int idx = nc >> 4;
            float ax = anchor_s(idx >> 4);
            float ay = anchor_s(idx & 15);
            float dxv = pvx - ax, dyv = pvy - ay;
            float bxy = fmaf(dxv, dxv, dyv*dyv);
            unsigned u[8];
            #pragma unroll
            for (int jj = 0; jj < 8; ++jj) {
                float d0 = sqrtf(bxy + dz2_[2*jj]);
                float d1 = sqrtf(bxy + dz2_[2*jj+1]);
                float p0 = fexp2(pml - d0);
                float p1 = fexp2(pml - d1);
                asm("v_cvt_pk_bf16_f32 %0, %1, %2" : "=v"(u[jj]) : "v"(p0), "v"(p1));
            }
            int pb = pv * 8;
            sP[pb + ((png*2    ) ^ (pv & 7))] = make_uint4(u[0],u[1],u[2],u[3]);
            sP[pb + ((png*2 + 1) ^ (pv & 7))] = make_uint4(u[4],u[5],u[6],u[7]);
        }
        __syncthreads();
        // ---- MFMA ----
        #pragma unroll
        for (int kss = 0; kss < 2; ++kss) {
            int blk = kss*4 + g;
            int va0 = wr*32 + r;
            int va1 = va0 + 16;
            short8 a0 = *(const short8*)&sP[va0*8 + (blk ^ (va0 & 7))];
            short8 a1 = *(const short8*)&sP[va1*8 + (blk ^ (va1 & 7))];
            #pragma unroll
            for (int df = 0; df < 4; ++df) {
                int dr = wc*64 + df*16 + r;
                short8 bb = *(const short8*)&sXT[dr*8 + (blk ^ (dr & 7))];
                acc[0][df] = __builtin_amdgcn_mfma_f32_16x16x32_bf16(a0, bb, acc[0][df], 0, 0, 0);
                acc[1][df] = __builtin_amdgcn_mfma_f32_16x16x32_bf16(a1, bb, acc[1][df], 0, 0, 0);
            }
        }
    }

    // ---- epilogue: plain stores into this kseg's partial buffer ----
    float* fp = fused_p + (size_t)ks_ * NV_ * HID_;
    #pragma unroll
    for (int vi = 0; vi < 2; ++vi)
        #pragma unroll
        for (int df = 0; df < 4; ++df)
            #pragma unroll
            for (int q = 0; q < 4; ++q) {
                int vloc = wr*32 + vi*16 + g*4 + q;
                int dcol = wc*64 + df*16 + r;
                if (vloc < nv) {
                    fp[(size_t)svid[vloc]*HID_ + dcol] = acc[vi][df][q];
                }
            }
}

// ------------- reduce: fused[v,d] = (sum_ks partial[ks][v,d]) * il[v] -------------
__global__ __launch_bounds__(256) void reduce_kernel(
    const float* __restrict__ fused_p, const float2* __restrict__ ml,
    float* __restrict__ fused)
{
    int idx = blockIdx.x * 256 + threadIdx.x;   // float4 index over NV*HID/4
    int v = idx >> 5;                            // 32 float4 per row
    float il = ml[v].y;
    const size_t stride = (size_t)NV_ * HID_ / 4;
    const float4* p = (const float4*)fused_p + idx;
    float4 a = p[0], b = p[stride], c = p[2*stride], d = p[3*stride];
    float4 o;
    o.x = (a.x + b.x + c.x + d.x) * il;
    o.y = (a.y + b.y + c.y + d.y) * il;
    o.z = (a.z + b.z + c.z + d.z) * il;
    o.w = (a.w + b.w + c.w + d.w) * il;
    ((float4*)fused)[idx] = o;
}

// ------------- output: full-coverage coalesced write, 4 locs/thread, float4 ops -------------
__global__ __launch_bounds__(256) void out_kernel(
    const int* __restrict__ map, const float* __restrict__ fused,
    float* __restrict__ out)
{
    int q = blockIdx.x * 256 + threadIdx.x;     // quad id, LOCS/4
    int loc0 = q << 2;
    int b   = loc0 >> 18;
    int rem = loc0 & (PLANE - 1);
    int4 vv = ((const int4*)map)[q];
    const float4* r0 = (const float4*)(fused + (size_t)(vv.x < 0 ? 0 : vv.x) * HID_);
    const float4* r1 = (const float4*)(fused + (size_t)(vv.y < 0 ? 0 : vv.y) * HID_);
    const float4* r2 = (const float4*)(fused + (size_t)(vv.z < 0 ? 0 : vv.z) * HID_);
    const float4* r3 = (const float4*)(fused + (size_t)(vv.w < 0 ? 0 : vv.w) * HID_);
    size_t obase = ((size_t)b * HID_) * PLANE + rem;
    const float4 z4 = make_float4(0.f, 0.f, 0.f, 0.f);
    #pragma unroll 4
    for (int chb = 0; chb < 32; ++chb) {
        float4 a = (vv.x >= 0) ? r0[chb] : z4;
        float4 c = (vv.y >= 0) ? r1[chb] : z4;
        float4 d = (vv.z >= 0) ? r2[chb] : z4;
        float4 e = (vv.w >= 0) ? r3[chb] : z4;
        *(float4*)&out[obase + (size_t)(chb*4 + 0) * PLANE] = make_float4(a.x, c.x, d.x, e.x);
        *(float4*)&out[obase + (size_t)(chb*4 + 1) * PLANE] = make_float4(a.y, c.y, d.y, e.y);
        *(float4*)&out[obase + (size_t)(chb*4 + 2) * PLANE] = make_float4(a.z, c.z, d.z, e.z);
        *(float4*)&out[obase + (size_t)(chb*4 + 3) * PLANE] = make_float4(a.w, c.w, d.w, e.w);
    }
}

extern "C" void kernel_launch(void* const* d_in, const int* in_sizes, int n_in,
                              void* d_out, int out_size, void* d_ws, size_t ws_size,
                              hipStream_t stream) {
    const float* pos = (const float*)d_in[0];
    const float* scl = (const float*)d_in[1];
    const float* rot = (const float*)d_in[2];
    const float* opa = (const float*)d_in[3];
    const float* W1  = (const float*)d_in[4];
    const float* b1  = (const float*)d_in[5];
    const float* W2  = (const float*)d_in[6];
    const float* b2  = (const float*)d_in[7];
    const int*   vc  = (const int*)d_in[8];
    float* out = (float*)d_out;

    char* ws = (char*)d_ws;
    unsigned short* xwT = (unsigned short*)(ws);        // 2 MB: bf16 x^T [b][128][4096]
    float2* ml      = (float2*)(ws + (2u<<20));         // 256 KB
    float*  fused   = (float*) (ws + (4u<<20));         // 16 MB
    float*  fused_p = (float*) (ws + (20u<<20));        // 64 MB: KS partial buffers
    int*    map     = (int*)   (ws + (84u<<20));        // 2 MB
    int*    vlist   = (int*)   (ws + (86u<<20));        // 256 KB
    int*    cnt     = (int*)   (ws + (87u<<20));        // 8 B

    hipMemsetAsync(map, 0xFF, LOCS*sizeof(int), stream);
    hipMemsetAsync(cnt, 0, 2*sizeof(int), stream);

    mlp_kernel<<<(B_*N_)/2, 256, 0, stream>>>(pos, scl, rot, opa, W1, b1, W2, b2, xwT);
    scatter_kernel<<<NV_/256, 256, 0, stream>>>(vc, map, cnt, vlist);
    ml_kernel<<<(NV_*8)/256, 256, 0, stream>>>(vc, ml);
    fuse_kernel<<<2*512*KS, 256, 0, stream>>>(xwT, ml, vc, vlist, cnt, fused_p);
    reduce_kernel<<<(NV_*HID_/4)/256, 256, 0, stream>>>(fused_p, ml, fused);
    out_kernel<<<LOCS/(256*4), 256, 0, stream>>>(map, fused, out);
}